// Round 1
// baseline (1584.564 us; speedup 1.0000x reference)
//
#include <hip/hip_runtime.h>

#define HEADS 8
#define NEG 0.2f

// ---------------------------------------------------------------------------
// Kernel A: h = feats @ W  (N x 128 @ 128 x 128), and out = h + bias
// W staged in LDS (64 KB). 64 nodes per block, 256 threads: thread t handles
// node i = t/4, column-float4 groups g = (t%4) + 4*ci, ci in [0,8).
// ---------------------------------------------------------------------------
__global__ __launch_bounds__(256) void k_gemm(const float* __restrict__ feats,
                                              const float* __restrict__ W,
                                              const float* __restrict__ bias,
                                              float* __restrict__ h,
                                              float* __restrict__ out,
                                              int N) {
    __shared__ float Wl[128 * 128];   // 64 KB
    const int t = threadIdx.x;
    const int n0 = blockIdx.x * 64;

    // stage W: 16384 floats = 4096 float4, 16 per thread, coalesced
    {
        const float4* Wg = (const float4*)W;
        float4* Wd = (float4*)Wl;
        #pragma unroll
        for (int i = 0; i < 16; ++i) Wd[t + 256 * i] = Wg[t + 256 * i];
    }
    __syncthreads();

    const int j = t & 3;
    const int i = t >> 2;          // node within tile
    const int n = n0 + i;

    float4 acc[8];
    #pragma unroll
    for (int ci = 0; ci < 8; ++ci) acc[ci] = make_float4(0.f, 0.f, 0.f, 0.f);

    const float4* W4 = (const float4*)Wl;
    const float4* f4 = (const float4*)feats;
    const bool valid = (n < N);

    #pragma unroll 2
    for (int k4 = 0; k4 < 32; ++k4) {
        float4 f = valid ? f4[(size_t)n * 32 + k4] : make_float4(0.f, 0.f, 0.f, 0.f);
        #pragma unroll
        for (int kk = 0; kk < 4; ++kk) {
            int k = k4 * 4 + kk;
            float fs = kk == 0 ? f.x : kk == 1 ? f.y : kk == 2 ? f.z : f.w;
            #pragma unroll
            for (int ci = 0; ci < 8; ++ci) {
                float4 w = W4[k * 32 + j + 4 * ci];   // 4 distinct addrs/wave, 16-way bcast
                acc[ci].x += fs * w.x;
                acc[ci].y += fs * w.y;
                acc[ci].z += fs * w.z;
                acc[ci].w += fs * w.w;
            }
        }
    }

    if (valid) {
        #pragma unroll
        for (int ci = 0; ci < 8; ++ci) {
            int g = j + 4 * ci;
            float4 b = ((const float4*)bias)[g];
            float4 a = acc[ci];
            ((float4*)h)[(size_t)n * 32 + g] = a;
            ((float4*)out)[(size_t)n * 32 + g] =
                make_float4(a.x + b.x, a.y + b.y, a.z + b.z, a.w + b.w);
        }
    }
}

// ---------------------------------------------------------------------------
// Kernel B: el[n,h] = <h[n,h,:], attn_l[h,:]>, er likewise. Thread per (n,head).
// ---------------------------------------------------------------------------
__global__ __launch_bounds__(256) void k_eler(const float* __restrict__ h,
                                              const float* __restrict__ attn_l,
                                              const float* __restrict__ attn_r,
                                              float* __restrict__ el,
                                              float* __restrict__ er,
                                              int N) {
    int t = blockIdx.x * 256 + threadIdx.x;   // t = n*8 + head
    int n = t >> 3, hd = t & 7;
    if (n >= N) return;
    const float4* hp = (const float4*)(h + (size_t)n * 128 + hd * 16);
    const float4* al = (const float4*)(attn_l + hd * 16);
    const float4* ar = (const float4*)(attn_r + hd * 16);
    float sl = 0.f, sr = 0.f;
    #pragma unroll
    for (int q = 0; q < 4; ++q) {
        float4 hv = hp[q], a = al[q], b = ar[q];
        sl += hv.x * a.x + hv.y * a.y + hv.z * a.z + hv.w * a.w;
        sr += hv.x * b.x + hv.y * b.y + hv.z * b.z + hv.w * b.w;
    }
    el[t] = sl;
    er[t] = sr;
}

// ---------------------------------------------------------------------------
// Kernel C: per (edge, head): p = exp(leaky(el[src]+er[dst])); seg[dst,h] += p
// (segment-max skipped: alpha is invariant to it and e is O(5) in fp32)
// ---------------------------------------------------------------------------
__global__ __launch_bounds__(256) void k_scores(const int* __restrict__ src,
                                                const int* __restrict__ dst,
                                                const float* __restrict__ el,
                                                const float* __restrict__ er,
                                                float* __restrict__ seg,
                                                int E) {
    int t = blockIdx.x * 256 + threadIdx.x;
    int e = t >> 3, hd = t & 7;
    if (e >= E) return;
    int s = src[e], d = dst[e];
    float x = el[s * 8 + hd] + er[d * 8 + hd];
    x = x > 0.f ? x : NEG * x;
    unsafeAtomicAdd(&seg[d * 8 + hd], __expf(x));
}

// seg -> 1/seg (0 stays 0 for zero-in-degree nodes)
__global__ __launch_bounds__(256) void k_recip(float* __restrict__ seg, int M) {
    int t = blockIdx.x * 256 + threadIdx.x;
    if (t < M) {
        float v = seg[t];
        seg[t] = v > 0.f ? 1.f / v : 0.f;
    }
}

// ---------------------------------------------------------------------------
// Kernel D: aggregation. 64 threads per edge; thread j covers cols {2j,2j+1},
// head = j/8. alpha recomputed (el/er/seg are LLC-hot); h[src] gathered as
// float2 (coalesced 512B per edge); scatter-add into out[dst] (fp32 atomics).
// ---------------------------------------------------------------------------
__global__ __launch_bounds__(256) void k_agg(const int* __restrict__ src,
                                             const int* __restrict__ dst,
                                             const float* __restrict__ el,
                                             const float* __restrict__ er,
                                             const float* __restrict__ seginv,
                                             const float* __restrict__ h,
                                             float* __restrict__ out,
                                             int E) {
    int t = blockIdx.x * 256 + threadIdx.x;
    int e = t >> 6;
    int j = t & 63;
    if (e >= E) return;
    int hd = j >> 3;
    int s = src[e], d = dst[e];
    float x = el[s * 8 + hd] + er[d * 8 + hd];
    x = x > 0.f ? x : NEG * x;
    float alpha = __expf(x) * seginv[d * 8 + hd];
    float2 hv = *(const float2*)(h + (size_t)s * 128 + 2 * j);
    unsafeAtomicAdd(&out[(size_t)d * 128 + 2 * j], alpha * hv.x);
    unsafeAtomicAdd(&out[(size_t)d * 128 + 2 * j + 1], alpha * hv.y);
}

extern "C" void kernel_launch(void* const* d_in, const int* in_sizes, int n_in,
                              void* d_out, int out_size, void* d_ws, size_t ws_size,
                              hipStream_t stream) {
    const float* feats  = (const float*)d_in[0];
    const float* W      = (const float*)d_in[1];
    const float* attn_l = (const float*)d_in[2];
    const float* attn_r = (const float*)d_in[3];
    const float* bias   = (const float*)d_in[4];
    const int*   src    = (const int*)d_in[5];
    const int*   dst    = (const int*)d_in[6];

    const int N = in_sizes[0] / 128;
    const int E = in_sizes[5];

    float* out = (float*)d_out;
    float* h   = (float*)d_ws;                 // N*128
    float* el  = h  + (size_t)N * 128;         // N*8
    float* er  = el + (size_t)N * 8;           // N*8
    float* seg = er + (size_t)N * 8;           // N*8

    hipMemsetAsync(seg, 0, (size_t)N * 8 * sizeof(float), stream);

    k_gemm  <<<(N + 63) / 64,               256, 0, stream>>>(feats, W, bias, h, out, N);
    k_eler  <<<(N * 8 + 255) / 256,         256, 0, stream>>>(h, attn_l, attn_r, el, er, N);
    k_scores<<<(E * 8 + 255) / 256,         256, 0, stream>>>(src, dst, el, er, seg, E);
    k_recip <<<(N * 8 + 255) / 256,         256, 0, stream>>>(seg, N * 8);
    k_agg   <<<(int)(((size_t)E * 64 + 255) / 256), 256, 0, stream>>>(src, dst, el, er, seg, h, out, E);
}

// Round 2
// 566.366 us; speedup vs baseline: 2.7978x; 2.7978x over previous
//
#include <hip/hip_runtime.h>

#define NEG 0.2f

// ---------------------------------------------------------------------------
// Kernel A: h = feats @ W  (N x 128 @ 128 x 128). W staged in LDS (64 KB).
// 64 nodes/block, 256 threads: thread t -> node t/4, col-float4 groups
// g = (t%4) + 4*ci.
// ---------------------------------------------------------------------------
__global__ __launch_bounds__(256) void k_gemm(const float* __restrict__ feats,
                                              const float* __restrict__ W,
                                              float* __restrict__ h,
                                              int N) {
    __shared__ float Wl[128 * 128];   // 64 KB
    const int t = threadIdx.x;
    const int n0 = blockIdx.x * 64;

    {
        const float4* Wg = (const float4*)W;
        float4* Wd = (float4*)Wl;
        #pragma unroll
        for (int i = 0; i < 16; ++i) Wd[t + 256 * i] = Wg[t + 256 * i];
    }
    __syncthreads();

    const int j = t & 3;
    const int i = t >> 2;
    const int n = n0 + i;

    float4 acc[8];
    #pragma unroll
    for (int ci = 0; ci < 8; ++ci) acc[ci] = make_float4(0.f, 0.f, 0.f, 0.f);

    const float4* W4 = (const float4*)Wl;
    const float4* f4 = (const float4*)feats;
    const bool valid = (n < N);

    #pragma unroll 2
    for (int k4 = 0; k4 < 32; ++k4) {
        float4 f = valid ? f4[(size_t)n * 32 + k4] : make_float4(0.f, 0.f, 0.f, 0.f);
        #pragma unroll
        for (int kk = 0; kk < 4; ++kk) {
            int k = k4 * 4 + kk;
            float fs = kk == 0 ? f.x : kk == 1 ? f.y : kk == 2 ? f.z : f.w;
            #pragma unroll
            for (int ci = 0; ci < 8; ++ci) {
                float4 w = W4[k * 32 + j + 4 * ci];
                acc[ci].x += fs * w.x;
                acc[ci].y += fs * w.y;
                acc[ci].z += fs * w.z;
                acc[ci].w += fs * w.w;
            }
        }
    }

    if (valid) {
        #pragma unroll
        for (int ci = 0; ci < 8; ++ci)
            ((float4*)h)[(size_t)n * 32 + j + 4 * ci] = acc[ci];
    }
}

// ---------------------------------------------------------------------------
// Kernel B: el/er per (node, head).
// ---------------------------------------------------------------------------
__global__ __launch_bounds__(256) void k_eler(const float* __restrict__ h,
                                              const float* __restrict__ attn_l,
                                              const float* __restrict__ attn_r,
                                              float* __restrict__ el,
                                              float* __restrict__ er,
                                              int N) {
    int t = blockIdx.x * 256 + threadIdx.x;   // t = n*8 + head
    int n = t >> 3, hd = t & 7;
    if (n >= N) return;
    const float4* hp = (const float4*)(h + (size_t)n * 128 + hd * 16);
    const float4* al = (const float4*)(attn_l + hd * 16);
    const float4* ar = (const float4*)(attn_r + hd * 16);
    float sl = 0.f, sr = 0.f;
    #pragma unroll
    for (int q = 0; q < 4; ++q) {
        float4 hv = hp[q], a = al[q], b = ar[q];
        sl += hv.x * a.x + hv.y * a.y + hv.z * a.z + hv.w * a.w;
        sr += hv.x * b.x + hv.y * b.y + hv.z * b.z + hv.w * b.w;
    }
    el[t] = sl;
    er[t] = sr;
}

// ---------------------------------------------------------------------------
// CSR build: degree count -> exclusive scan (3 kernels) -> fill.
// ---------------------------------------------------------------------------
__global__ __launch_bounds__(256) void k_deg(const int* __restrict__ dst,
                                             int* __restrict__ deg, int E) {
    int e = blockIdx.x * 256 + threadIdx.x;
    if (e < E) atomicAdd(&deg[dst[e]], 1);
}

// block b scans 1024 elements (thread t: 4 contiguous), writes block-local
// exclusive scan to rowptr and the block total to partial[b].
__global__ __launch_bounds__(256) void k_scan1(const int* __restrict__ deg,
                                               int* __restrict__ rowptr,
                                               int* __restrict__ partial, int N) {
    __shared__ int sd[256];
    int b = blockIdx.x, t = threadIdx.x;
    int base = b * 1024 + t * 4;
    int v0 = 0, v1 = 0, v2 = 0, v3 = 0;
    if (base + 3 < N) {
        int4 d4 = *(const int4*)(deg + base);
        v0 = d4.x; v1 = d4.y; v2 = d4.z; v3 = d4.w;
    } else {
        if (base + 0 < N) v0 = deg[base];
        if (base + 1 < N) v1 = deg[base + 1];
        if (base + 2 < N) v2 = deg[base + 2];
    }
    int tsum = v0 + v1 + v2 + v3;
    sd[t] = tsum;
    __syncthreads();
    for (int off = 1; off < 256; off <<= 1) {
        int x = (t >= off) ? sd[t - off] : 0;
        __syncthreads();
        sd[t] += x;
        __syncthreads();
    }
    int ex = sd[t] - tsum;   // exclusive prefix of thread sums within block
    if (base     < N) rowptr[base]     = ex;
    if (base + 1 < N) rowptr[base + 1] = ex + v0;
    if (base + 2 < N) rowptr[base + 2] = ex + v0 + v1;
    if (base + 3 < N) rowptr[base + 3] = ex + v0 + v1 + v2;
    if (t == 255) partial[b] = sd[255];
}

__global__ void k_scan2(const int* __restrict__ partial,
                        int* __restrict__ partial_ex, int B) {
    if (threadIdx.x == 0 && blockIdx.x == 0) {
        int run = 0;
        for (int i = 0; i < B; ++i) { partial_ex[i] = run; run += partial[i]; }
    }
}

__global__ __launch_bounds__(256) void k_scan3(int* __restrict__ rowptr,
                                               int* __restrict__ cursor,
                                               const int* __restrict__ partial_ex,
                                               int N, int E) {
    int b = blockIdx.x, t = threadIdx.x;
    int add = partial_ex[b];
    int base = b * 1024 + t * 4;
    #pragma unroll
    for (int q = 0; q < 4; ++q) {
        int i = base + q;
        if (i < N) { int v = rowptr[i] + add; rowptr[i] = v; cursor[i] = v; }
    }
    if (b == 0 && t == 0) rowptr[N] = E;
}

__global__ __launch_bounds__(256) void k_fill(const int* __restrict__ src,
                                              const int* __restrict__ dst,
                                              int* __restrict__ cursor,
                                              int* __restrict__ csr_src, int E) {
    int e = blockIdx.x * 256 + threadIdx.x;
    if (e >= E) return;
    int d = dst[e];
    int p = atomicAdd(&cursor[d], 1);
    csr_src[p] = src[e];
}

// ---------------------------------------------------------------------------
// Kernel D: gather-style aggregation. One wave per node; lane j covers cols
// {2j,2j+1}, head = j/8. Accumulates unnormalized Σ w·h[src] and Σ w in
// registers (softmax-max skipped: scores are O(±4), alpha invariant), then
// writes out = acc/Σw + h[n] + bias once, coalesced, atomic-free.
// ---------------------------------------------------------------------------
__global__ __launch_bounds__(256) void k_agg(const int* __restrict__ rowptr,
                                             const int* __restrict__ csr_src,
                                             const float* __restrict__ el,
                                             const float* __restrict__ er,
                                             const float* __restrict__ h,
                                             const float* __restrict__ bias,
                                             float* __restrict__ out, int N) {
    int t = threadIdx.x;
    int n = blockIdx.x * 4 + (t >> 6);
    int j = t & 63;
    if (n >= N) return;
    int hd = j >> 3;
    int begin = rowptr[n], end = rowptr[n + 1];
    float erv = er[n * 8 + hd];
    float accx = 0.f, accy = 0.f, expsum = 0.f;
    for (int p = begin; p < end; ++p) {
        int s = csr_src[p];                       // wave-uniform
        float x = el[s * 8 + hd] + erv;
        x = x > 0.f ? x : NEG * x;
        float w = __expf(x);
        float2 hv = *(const float2*)(h + (size_t)s * 128 + 2 * j);
        accx += w * hv.x;
        accy += w * hv.y;
        expsum += w;
    }
    float inv = expsum > 0.f ? 1.f / expsum : 0.f;
    float2 hn = *(const float2*)(h + (size_t)n * 128 + 2 * j);
    float2 bv = *(const float2*)(bias + 2 * j);
    float2 o;
    o.x = accx * inv + hn.x + bv.x;
    o.y = accy * inv + hn.y + bv.y;
    *(float2*)(out + (size_t)n * 128 + 2 * j) = o;
}

extern "C" void kernel_launch(void* const* d_in, const int* in_sizes, int n_in,
                              void* d_out, int out_size, void* d_ws, size_t ws_size,
                              hipStream_t stream) {
    const float* feats  = (const float*)d_in[0];
    const float* W      = (const float*)d_in[1];
    const float* attn_l = (const float*)d_in[2];
    const float* attn_r = (const float*)d_in[3];
    const float* bias   = (const float*)d_in[4];
    const int*   src    = (const int*)d_in[5];
    const int*   dst    = (const int*)d_in[6];

    const int N = in_sizes[0] / 128;
    const int E = in_sizes[5];
    const int B1 = (N + 1023) / 1024;   // scan blocks (98 for N=100k)

    float* out = (float*)d_out;
    char*  ws  = (char*)d_ws;
    float* h       = (float*)ws;                       ws += (size_t)N * 128 * 4;
    float* el      = (float*)ws;                       ws += (size_t)N * 8 * 4;
    float* er      = (float*)ws;                       ws += (size_t)N * 8 * 4;
    int*   deg     = (int*)ws;                         ws += (size_t)N * 4;
    int*   rowptr  = (int*)ws;                         ws += (size_t)(N + 1) * 4;
    int*   cursor  = (int*)ws;                         ws += (size_t)N * 4;
    int*   partial = (int*)ws;                         ws += 256 * 4;
    int*   partial_ex = (int*)ws;                      ws += 256 * 4;
    int*   csr_src = (int*)ws;                         ws += (size_t)E * 4;

    hipMemsetAsync(deg, 0, (size_t)N * sizeof(int), stream);

    k_gemm <<<(N + 63) / 64,       256, 0, stream>>>(feats, W, h, N);
    k_eler <<<(N * 8 + 255) / 256, 256, 0, stream>>>(h, attn_l, attn_r, el, er, N);
    k_deg  <<<(E + 255) / 256,     256, 0, stream>>>(dst, deg, E);
    k_scan1<<<B1,                  256, 0, stream>>>(deg, rowptr, partial, N);
    k_scan2<<<1,                    64, 0, stream>>>(partial, partial_ex, B1);
    k_scan3<<<B1,                  256, 0, stream>>>(rowptr, cursor, partial_ex, N, E);
    k_fill <<<(E + 255) / 256,     256, 0, stream>>>(src, dst, cursor, csr_src, E);
    k_agg  <<<(N + 3) / 4,         256, 0, stream>>>(rowptr, csr_src, el, er, h, bias, out, N);
}

// Round 3
// 417.898 us; speedup vs baseline: 3.7918x; 1.3553x over previous
//
#include <hip/hip_runtime.h>

#define NEG 0.2f

using bf16x8 = __attribute__((ext_vector_type(8))) short;
using f32x4  = __attribute__((ext_vector_type(4))) float;

__device__ __forceinline__ short f2bf(float f) {   // RNE round to bf16 bits
    union { float f; unsigned u; } v; v.f = f;
    unsigned r = v.u + 0x7FFFu + ((v.u >> 16) & 1u);
    return (short)(r >> 16);
}
__device__ __forceinline__ float bflo(unsigned v) {
    union { unsigned u; float f; } x; x.u = v << 16; return x.f;
}
__device__ __forceinline__ float bfhi(unsigned v) {
    union { unsigned u; float f; } x; x.u = v & 0xffff0000u; return x.f;
}

// ---------------------------------------------------------------------------
// Kernel A: h(bf16) = bf16(feats) @ bf16(W) via mfma_f32_16x16x32_bf16.
// Block = 256 thr = 4 waves, 64 rows. W^T staged in LDS as bf16, col-major
// rows padded to 136 shorts (uniform 8-phase ds_read_b128, no conflicts).
// Each wave: 16 rows x 128 cols = 8 tiles, K=128 in 4 chunks of 32.
// ---------------------------------------------------------------------------
__global__ __launch_bounds__(256) void k_gemm(const float* __restrict__ feats,
                                              const float* __restrict__ W,
                                              unsigned short* __restrict__ h,
                                              int N) {
    __shared__ short Wt[128 * 136];   // Wt[col][k], 34816 B
    const int t = threadIdx.x;
    const int n0 = blockIdx.x * 64;

    // stage W^T as bf16: idx = k*128 + c -> Wt[c*136 + k]
    #pragma unroll
    for (int i = 0; i < 64; ++i) {
        int idx = t + 256 * i;
        int k = idx >> 7, c = idx & 127;
        Wt[c * 136 + k] = f2bf(W[idx]);
    }
    __syncthreads();

    const int w    = t >> 6;
    const int lane = t & 63;
    const int m    = lane & 15;
    const int quad = lane >> 4;
    const int kq   = quad * 8;

    const int row_a = n0 + w * 16 + m;
    const bool va = (row_a < N);

    f32x4 acc[8];
    #pragma unroll
    for (int ti = 0; ti < 8; ++ti) acc[ti] = (f32x4){0.f, 0.f, 0.f, 0.f};

    #pragma unroll
    for (int kc = 0; kc < 4; ++kc) {
        const float* ap = feats + (size_t)row_a * 128 + kc * 32 + kq;
        float4 a0 = va ? ((const float4*)ap)[0] : make_float4(0.f,0.f,0.f,0.f);
        float4 a1 = va ? ((const float4*)ap)[1] : make_float4(0.f,0.f,0.f,0.f);
        bf16x8 af;
        af[0] = f2bf(a0.x); af[1] = f2bf(a0.y); af[2] = f2bf(a0.z); af[3] = f2bf(a0.w);
        af[4] = f2bf(a1.x); af[5] = f2bf(a1.y); af[6] = f2bf(a1.z); af[7] = f2bf(a1.w);
        #pragma unroll
        for (int ti = 0; ti < 8; ++ti) {
            bf16x8 bf = *(const bf16x8*)&Wt[(ti * 16 + m) * 136 + kc * 32 + kq];
            acc[ti] = __builtin_amdgcn_mfma_f32_16x16x32_bf16(af, bf, acc[ti], 0, 0, 0);
        }
    }

    // C layout: col = lane&15 (+16*ti), row = quad*4 + r
    const int row_d = n0 + w * 16 + quad * 4;
    #pragma unroll
    for (int ti = 0; ti < 8; ++ti) {
        int col = ti * 16 + m;
        #pragma unroll
        for (int r = 0; r < 4; ++r) {
            int row = row_d + r;
            if (row < N) h[(size_t)row * 128 + col] = (unsigned short)f2bf(acc[ti][r]);
        }
    }
}

// ---------------------------------------------------------------------------
// Kernel B: el/er per (node, head) from bf16 h.
// ---------------------------------------------------------------------------
__global__ __launch_bounds__(256) void k_eler(const unsigned short* __restrict__ h,
                                              const float* __restrict__ attn_l,
                                              const float* __restrict__ attn_r,
                                              float* __restrict__ el,
                                              float* __restrict__ er,
                                              int N) {
    int t = blockIdx.x * 256 + threadIdx.x;   // t = n*8 + head
    int n = t >> 3, hd = t & 7;
    if (n >= N) return;
    const uint4* hp = (const uint4*)(h + (size_t)n * 128 + hd * 16);
    uint4 u0 = hp[0], u1 = hp[1];
    const float4* al = (const float4*)(attn_l + hd * 16);
    const float4* ar = (const float4*)(attn_r + hd * 16);
    float hv[16];
    hv[0]=bflo(u0.x); hv[1]=bfhi(u0.x); hv[2]=bflo(u0.y); hv[3]=bfhi(u0.y);
    hv[4]=bflo(u0.z); hv[5]=bfhi(u0.z); hv[6]=bflo(u0.w); hv[7]=bfhi(u0.w);
    hv[8]=bflo(u1.x); hv[9]=bfhi(u1.x); hv[10]=bflo(u1.y); hv[11]=bfhi(u1.y);
    hv[12]=bflo(u1.z); hv[13]=bfhi(u1.z); hv[14]=bflo(u1.w); hv[15]=bfhi(u1.w);
    float sl = 0.f, sr = 0.f;
    #pragma unroll
    for (int q = 0; q < 4; ++q) {
        float4 a = al[q], b = ar[q];
        sl += hv[4*q]*a.x + hv[4*q+1]*a.y + hv[4*q+2]*a.z + hv[4*q+3]*a.w;
        sr += hv[4*q]*b.x + hv[4*q+1]*b.y + hv[4*q+2]*b.z + hv[4*q+3]*b.w;
    }
    el[t] = sl;
    er[t] = sr;
}

// ---------------------------------------------------------------------------
// CSR build: degree -> scan -> fill.
// ---------------------------------------------------------------------------
__global__ __launch_bounds__(256) void k_deg(const int* __restrict__ dst,
                                             int* __restrict__ deg, int E) {
    int i = blockIdx.x * 256 + threadIdx.x;
    int e = i * 4;
    if (e + 3 < E) {
        int4 d4 = *(const int4*)(dst + e);
        atomicAdd(&deg[d4.x], 1); atomicAdd(&deg[d4.y], 1);
        atomicAdd(&deg[d4.z], 1); atomicAdd(&deg[d4.w], 1);
    } else {
        for (int q = e; q < E; ++q) atomicAdd(&deg[dst[q]], 1);
    }
}

__global__ __launch_bounds__(256) void k_scan1(const int* __restrict__ deg,
                                               int* __restrict__ rowptr,
                                               int* __restrict__ partial, int N) {
    __shared__ int sd[256];
    int b = blockIdx.x, t = threadIdx.x;
    int base = b * 1024 + t * 4;
    int v0 = 0, v1 = 0, v2 = 0, v3 = 0;
    if (base + 3 < N) {
        int4 d4 = *(const int4*)(deg + base);
        v0 = d4.x; v1 = d4.y; v2 = d4.z; v3 = d4.w;
    } else {
        if (base + 0 < N) v0 = deg[base];
        if (base + 1 < N) v1 = deg[base + 1];
        if (base + 2 < N) v2 = deg[base + 2];
    }
    int tsum = v0 + v1 + v2 + v3;
    sd[t] = tsum;
    __syncthreads();
    for (int off = 1; off < 256; off <<= 1) {
        int x = (t >= off) ? sd[t - off] : 0;
        __syncthreads();
        sd[t] += x;
        __syncthreads();
    }
    int ex = sd[t] - tsum;
    if (base     < N) rowptr[base]     = ex;
    if (base + 1 < N) rowptr[base + 1] = ex + v0;
    if (base + 2 < N) rowptr[base + 2] = ex + v0 + v1;
    if (base + 3 < N) rowptr[base + 3] = ex + v0 + v1 + v2;
    if (t == 255) partial[b] = sd[255];
}

__global__ void k_scan2(const int* __restrict__ partial,
                        int* __restrict__ partial_ex, int B) {
    if (threadIdx.x == 0 && blockIdx.x == 0) {
        int run = 0;
        for (int i = 0; i < B; ++i) { partial_ex[i] = run; run += partial[i]; }
    }
}

__global__ __launch_bounds__(256) void k_scan3(int* __restrict__ rowptr,
                                               int* __restrict__ cursor,
                                               const int* __restrict__ partial_ex,
                                               int N, int E) {
    int b = blockIdx.x, t = threadIdx.x;
    int add = partial_ex[b];
    int base = b * 1024 + t * 4;
    #pragma unroll
    for (int q = 0; q < 4; ++q) {
        int i = base + q;
        if (i < N) { int v = rowptr[i] + add; rowptr[i] = v; cursor[i] = v; }
    }
    if (b == 0 && t == 0) rowptr[N] = E;
}

__global__ __launch_bounds__(256) void k_fill(const int* __restrict__ src,
                                              const int* __restrict__ dst,
                                              int* __restrict__ cursor,
                                              int* __restrict__ csr_src, int E) {
    int e = blockIdx.x * 256 + threadIdx.x;
    if (e >= E) return;
    int d = dst[e];
    int p = atomicAdd(&cursor[d], 1);
    csr_src[p] = src[e];
}

// ---------------------------------------------------------------------------
// Kernel D: gather aggregation, one wave per node, 4 edges in flight.
// Quarter q = lane>>4 processes edge p = begin+4i+q; lane covers cols
// 8*(lane&15)..+7 (16 B bf16 load). Combine quarters via shfl_xor(32,16);
// lanes 0..15 write the 512 B output row (atomic-free, coalesced).
// ---------------------------------------------------------------------------
__global__ __launch_bounds__(256) void k_agg(const int* __restrict__ rowptr,
                                             const int* __restrict__ csr_src,
                                             const float* __restrict__ el,
                                             const float* __restrict__ er,
                                             const unsigned short* __restrict__ h,
                                             const float* __restrict__ bias,
                                             float* __restrict__ out, int N) {
    int t = threadIdx.x;
    int n = blockIdx.x * 4 + (t >> 6);
    if (n >= N) return;
    int lane = t & 63;
    int q    = lane >> 4;      // edge slot 0..3
    int c16  = lane & 15;      // col group: cols 8*c16..8*c16+7
    int hd   = c16 >> 1;
    int begin = rowptr[n], end = rowptr[n + 1];
    float erv = er[n * 8 + hd];

    float acc[8] = {0.f,0.f,0.f,0.f,0.f,0.f,0.f,0.f};
    float expsum = 0.f;

    for (int p = begin + q; p < end; p += 4) {
        int s = csr_src[p];
        float x = el[s * 8 + hd] + erv;
        x = x > 0.f ? x : NEG * x;
        float w = __expf(x);
        expsum += w;
        uint4 hv = *(const uint4*)(h + (size_t)s * 128 + c16 * 8);
        acc[0] += w * bflo(hv.x); acc[1] += w * bfhi(hv.x);
        acc[2] += w * bflo(hv.y); acc[3] += w * bfhi(hv.y);
        acc[4] += w * bflo(hv.z); acc[5] += w * bfhi(hv.z);
        acc[6] += w * bflo(hv.w); acc[7] += w * bfhi(hv.w);
    }

    #pragma unroll
    for (int k = 0; k < 8; ++k) {
        acc[k] += __shfl_xor(acc[k], 32);
        acc[k] += __shfl_xor(acc[k], 16);
    }
    expsum += __shfl_xor(expsum, 32);
    expsum += __shfl_xor(expsum, 16);

    if (q == 0) {
        float inv = expsum > 0.f ? 1.f / expsum : 0.f;
        uint4 hn = *(const uint4*)(h + (size_t)n * 128 + c16 * 8);
        const float4* bp = (const float4*)(bias + c16 * 8);
        float4 b0 = bp[0], b1 = bp[1];
        float4 o0, o1;
        o0.x = acc[0]*inv + bflo(hn.x) + b0.x;
        o0.y = acc[1]*inv + bfhi(hn.x) + b0.y;
        o0.z = acc[2]*inv + bflo(hn.y) + b0.z;
        o0.w = acc[3]*inv + bfhi(hn.y) + b0.w;
        o1.x = acc[4]*inv + bflo(hn.z) + b1.x;
        o1.y = acc[5]*inv + bfhi(hn.z) + b1.y;
        o1.z = acc[6]*inv + bflo(hn.w) + b1.z;
        o1.w = acc[7]*inv + bfhi(hn.w) + b1.w;
        float4* op = (float4*)(out + (size_t)n * 128 + c16 * 8);
        op[0] = o0; op[1] = o1;
    }
}

extern "C" void kernel_launch(void* const* d_in, const int* in_sizes, int n_in,
                              void* d_out, int out_size, void* d_ws, size_t ws_size,
                              hipStream_t stream) {
    const float* feats  = (const float*)d_in[0];
    const float* W      = (const float*)d_in[1];
    const float* attn_l = (const float*)d_in[2];
    const float* attn_r = (const float*)d_in[3];
    const float* bias   = (const float*)d_in[4];
    const int*   src    = (const int*)d_in[5];
    const int*   dst    = (const int*)d_in[6];

    const int N = in_sizes[0] / 128;
    const int E = in_sizes[5];
    const int B1 = (N + 1023) / 1024;

    float* out = (float*)d_out;
    char*  ws  = (char*)d_ws;
    unsigned short* h = (unsigned short*)ws;           ws += (size_t)N * 128 * 2;
    float* el      = (float*)ws;                       ws += (size_t)N * 8 * 4;
    float* er      = (float*)ws;                       ws += (size_t)N * 8 * 4;
    int*   deg     = (int*)ws;                         ws += (size_t)N * 4;
    int*   rowptr  = (int*)ws;                         ws += (size_t)(N + 1) * 4;
    int*   cursor  = (int*)ws;                         ws += (size_t)N * 4;
    int*   partial = (int*)ws;                         ws += 256 * 4;
    int*   partial_ex = (int*)ws;                      ws += 256 * 4;
    int*   csr_src = (int*)ws;                         ws += (size_t)E * 4;

    hipMemsetAsync(deg, 0, (size_t)N * sizeof(int), stream);

    k_gemm <<<(N + 63) / 64,         256, 0, stream>>>(feats, W, h, N);
    k_eler <<<(N * 8 + 255) / 256,   256, 0, stream>>>(h, attn_l, attn_r, el, er, N);
    k_deg  <<<(E / 4 + 255) / 256,   256, 0, stream>>>(dst, deg, E);
    k_scan1<<<B1,                    256, 0, stream>>>(deg, rowptr, partial, N);
    k_scan2<<<1,                      64, 0, stream>>>(partial, partial_ex, B1);
    k_scan3<<<B1,                    256, 0, stream>>>(rowptr, cursor, partial_ex, N, E);
    k_fill <<<(E + 255) / 256,       256, 0, stream>>>(src, dst, cursor, csr_src, E);
    k_agg  <<<(N + 3) / 4,           256, 0, stream>>>(rowptr, csr_src, el, er, h, bias, out, N);
}

// Round 4
// 368.155 us; speedup vs baseline: 4.3041x; 1.1351x over previous
//
#include <hip/hip_runtime.h>

#define NEG 0.2f

using bf16x8 = __attribute__((ext_vector_type(8))) short;
using f32x4  = __attribute__((ext_vector_type(4))) float;

__device__ __forceinline__ short f2bf(float f) {   // RNE round to bf16 bits
    union { float f; unsigned u; } v; v.f = f;
    unsigned r = v.u + 0x7FFFu + ((v.u >> 16) & 1u);
    return (short)(r >> 16);
}
__device__ __forceinline__ float bflo(unsigned v) {
    union { unsigned u; float f; } x; x.u = v << 16; return x.f;
}
__device__ __forceinline__ float bfhi(unsigned v) {
    union { unsigned u; float f; } x; x.u = v & 0xffff0000u; return x.f;
}

// ---------------------------------------------------------------------------
// Kernel A: h(bf16) = bf16(feats) @ bf16(W) via mfma_f32_16x16x32_bf16.
// ---------------------------------------------------------------------------
__global__ __launch_bounds__(256) void k_gemm(const float* __restrict__ feats,
                                              const float* __restrict__ W,
                                              unsigned short* __restrict__ h,
                                              int N) {
    __shared__ short Wt[128 * 136];   // Wt[col][k], 34816 B
    const int t = threadIdx.x;
    const int n0 = blockIdx.x * 64;

    #pragma unroll
    for (int i = 0; i < 64; ++i) {
        int idx = t + 256 * i;
        int k = idx >> 7, c = idx & 127;
        Wt[c * 136 + k] = f2bf(W[idx]);
    }
    __syncthreads();

    const int w    = t >> 6;
    const int lane = t & 63;
    const int m    = lane & 15;
    const int quad = lane >> 4;
    const int kq   = quad * 8;

    const int row_a = n0 + w * 16 + m;
    const bool va = (row_a < N);

    f32x4 acc[8];
    #pragma unroll
    for (int ti = 0; ti < 8; ++ti) acc[ti] = (f32x4){0.f, 0.f, 0.f, 0.f};

    #pragma unroll
    for (int kc = 0; kc < 4; ++kc) {
        const float* ap = feats + (size_t)row_a * 128 + kc * 32 + kq;
        float4 a0 = va ? ((const float4*)ap)[0] : make_float4(0.f,0.f,0.f,0.f);
        float4 a1 = va ? ((const float4*)ap)[1] : make_float4(0.f,0.f,0.f,0.f);
        bf16x8 af;
        af[0] = f2bf(a0.x); af[1] = f2bf(a0.y); af[2] = f2bf(a0.z); af[3] = f2bf(a0.w);
        af[4] = f2bf(a1.x); af[5] = f2bf(a1.y); af[6] = f2bf(a1.z); af[7] = f2bf(a1.w);
        #pragma unroll
        for (int ti = 0; ti < 8; ++ti) {
            bf16x8 bf = *(const bf16x8*)&Wt[(ti * 16 + m) * 136 + kc * 32 + kq];
            acc[ti] = __builtin_amdgcn_mfma_f32_16x16x32_bf16(af, bf, acc[ti], 0, 0, 0);
        }
    }

    const int row_d = n0 + w * 16 + quad * 4;
    #pragma unroll
    for (int ti = 0; ti < 8; ++ti) {
        int col = ti * 16 + m;
        #pragma unroll
        for (int r = 0; r < 4; ++r) {
            int row = row_d + r;
            if (row < N) h[(size_t)row * 128 + col] = (unsigned short)f2bf(acc[ti][r]);
        }
    }
}

// ---------------------------------------------------------------------------
// Kernel B: el/er per (node, head) from bf16 h.
// ---------------------------------------------------------------------------
__global__ __launch_bounds__(256) void k_eler(const unsigned short* __restrict__ h,
                                              const float* __restrict__ attn_l,
                                              const float* __restrict__ attn_r,
                                              float* __restrict__ el,
                                              float* __restrict__ er,
                                              int N) {
    int t = blockIdx.x * 256 + threadIdx.x;   // t = n*8 + head
    int n = t >> 3, hd = t & 7;
    if (n >= N) return;
    const uint4* hp = (const uint4*)(h + (size_t)n * 128 + hd * 16);
    uint4 u0 = hp[0], u1 = hp[1];
    const float4* al = (const float4*)(attn_l + hd * 16);
    const float4* ar = (const float4*)(attn_r + hd * 16);
    float hv[16];
    hv[0]=bflo(u0.x); hv[1]=bfhi(u0.x); hv[2]=bflo(u0.y); hv[3]=bfhi(u0.y);
    hv[4]=bflo(u0.z); hv[5]=bfhi(u0.z); hv[6]=bflo(u0.w); hv[7]=bfhi(u0.w);
    hv[8]=bflo(u1.x); hv[9]=bfhi(u1.x); hv[10]=bflo(u1.y); hv[11]=bfhi(u1.y);
    hv[12]=bflo(u1.z); hv[13]=bfhi(u1.z); hv[14]=bflo(u1.w); hv[15]=bfhi(u1.w);
    float sl = 0.f, sr = 0.f;
    #pragma unroll
    for (int q = 0; q < 4; ++q) {
        float4 a = al[q], b = ar[q];
        sl += hv[4*q]*a.x + hv[4*q+1]*a.y + hv[4*q+2]*a.z + hv[4*q+3]*a.w;
        sr += hv[4*q]*b.x + hv[4*q+1]*b.y + hv[4*q+2]*b.z + hv[4*q+3]*b.w;
    }
    el[t] = sl;
    er[t] = sr;
}

// ---------------------------------------------------------------------------
// CSR build, dst-range partitioned: block (chunk c = blockIdx>>3,
// range r = blockIdx&7) processes edges of chunk c with dst in
// [r*N8, (r+1)*N8). Consecutive blockIdx round-robin across XCDs, so each
// deg/cursor/csr region is touched by (mostly) ONE XCD: atomic lines stay
// L2-local and csr_src lines fill densely before writeback. The 8x dst
// re-read is absorbed by L2/LLC (8 sibling blocks read the same chunk
// concurrently). Correct under ANY blockIdx->XCD mapping.
// ---------------------------------------------------------------------------
#define CHUNK 2048   // edges per block (256 thr x 8)

__global__ __launch_bounds__(256) void k_deg(const int* __restrict__ dst,
                                             int* __restrict__ deg,
                                             int E, int N8) {
    int r = blockIdx.x & 7;
    int c = blockIdx.x >> 3;
    int lo = r * N8, hi = lo + N8;
    int base = c * CHUNK + threadIdx.x;
    #pragma unroll
    for (int q = 0; q < 8; ++q) {
        int e = base + q * 256;
        if (e < E) {
            int d = dst[e];
            if (d >= lo && d < hi) atomicAdd(&deg[d], 1);
        }
    }
}

__global__ __launch_bounds__(256) void k_scan1(const int* __restrict__ deg,
                                               int* __restrict__ rowptr,
                                               int* __restrict__ partial, int N) {
    __shared__ int sd[256];
    int b = blockIdx.x, t = threadIdx.x;
    int base = b * 1024 + t * 4;
    int v0 = 0, v1 = 0, v2 = 0, v3 = 0;
    if (base + 3 < N) {
        int4 d4 = *(const int4*)(deg + base);
        v0 = d4.x; v1 = d4.y; v2 = d4.z; v3 = d4.w;
    } else {
        if (base + 0 < N) v0 = deg[base];
        if (base + 1 < N) v1 = deg[base + 1];
        if (base + 2 < N) v2 = deg[base + 2];
    }
    int tsum = v0 + v1 + v2 + v3;
    sd[t] = tsum;
    __syncthreads();
    for (int off = 1; off < 256; off <<= 1) {
        int x = (t >= off) ? sd[t - off] : 0;
        __syncthreads();
        sd[t] += x;
        __syncthreads();
    }
    int ex = sd[t] - tsum;
    if (base     < N) rowptr[base]     = ex;
    if (base + 1 < N) rowptr[base + 1] = ex + v0;
    if (base + 2 < N) rowptr[base + 2] = ex + v0 + v1;
    if (base + 3 < N) rowptr[base + 3] = ex + v0 + v1 + v2;
    if (t == 255) partial[b] = sd[255];
}

__global__ void k_scan2(const int* __restrict__ partial,
                        int* __restrict__ partial_ex, int B) {
    if (threadIdx.x == 0 && blockIdx.x == 0) {
        int run = 0;
        for (int i = 0; i < B; ++i) { partial_ex[i] = run; run += partial[i]; }
    }
}

__global__ __launch_bounds__(256) void k_scan3(int* __restrict__ rowptr,
                                               int* __restrict__ cursor,
                                               const int* __restrict__ partial_ex,
                                               int N, int E) {
    int b = blockIdx.x, t = threadIdx.x;
    int add = partial_ex[b];
    int base = b * 1024 + t * 4;
    #pragma unroll
    for (int q = 0; q < 4; ++q) {
        int i = base + q;
        if (i < N) { int v = rowptr[i] + add; rowptr[i] = v; cursor[i] = v; }
    }
    if (b == 0 && t == 0) rowptr[N] = E;
}

__global__ __launch_bounds__(256) void k_fill(const int* __restrict__ src,
                                              const int* __restrict__ dst,
                                              int* __restrict__ cursor,
                                              int* __restrict__ csr_src,
                                              int E, int N8) {
    int r = blockIdx.x & 7;
    int c = blockIdx.x >> 3;
    int lo = r * N8, hi = lo + N8;
    int base = c * CHUNK + threadIdx.x;
    #pragma unroll
    for (int q = 0; q < 8; ++q) {
        int e = base + q * 256;
        if (e < E) {
            int d = dst[e];
            if (d >= lo && d < hi) {
                int p = atomicAdd(&cursor[d], 1);
                csr_src[p] = src[e];
            }
        }
    }
}

// ---------------------------------------------------------------------------
// Kernel D: gather aggregation, one wave per node, 4 edges in flight.
// ---------------------------------------------------------------------------
__global__ __launch_bounds__(256) void k_agg(const int* __restrict__ rowptr,
                                             const int* __restrict__ csr_src,
                                             const float* __restrict__ el,
                                             const float* __restrict__ er,
                                             const unsigned short* __restrict__ h,
                                             const float* __restrict__ bias,
                                             float* __restrict__ out, int N) {
    int t = threadIdx.x;
    int n = blockIdx.x * 4 + (t >> 6);
    if (n >= N) return;
    int lane = t & 63;
    int q    = lane >> 4;      // edge slot 0..3
    int c16  = lane & 15;      // col group: cols 8*c16..8*c16+7
    int hd   = c16 >> 1;
    int begin = rowptr[n], end = rowptr[n + 1];
    float erv = er[n * 8 + hd];

    float acc[8] = {0.f,0.f,0.f,0.f,0.f,0.f,0.f,0.f};
    float expsum = 0.f;

    for (int p = begin + q; p < end; p += 4) {
        int s = csr_src[p];
        float x = el[s * 8 + hd] + erv;
        x = x > 0.f ? x : NEG * x;
        float w = __expf(x);
        expsum += w;
        uint4 hv = *(const uint4*)(h + (size_t)s * 128 + c16 * 8);
        acc[0] += w * bflo(hv.x); acc[1] += w * bfhi(hv.x);
        acc[2] += w * bflo(hv.y); acc[3] += w * bfhi(hv.y);
        acc[4] += w * bflo(hv.z); acc[5] += w * bfhi(hv.z);
        acc[6] += w * bflo(hv.w); acc[7] += w * bfhi(hv.w);
    }

    #pragma unroll
    for (int k = 0; k < 8; ++k) {
        acc[k] += __shfl_xor(acc[k], 32);
        acc[k] += __shfl_xor(acc[k], 16);
    }
    expsum += __shfl_xor(expsum, 32);
    expsum += __shfl_xor(expsum, 16);

    if (q == 0) {
        float inv = expsum > 0.f ? 1.f / expsum : 0.f;
        uint4 hn = *(const uint4*)(h + (size_t)n * 128 + c16 * 8);
        const float4* bp = (const float4*)(bias + c16 * 8);
        float4 b0 = bp[0], b1 = bp[1];
        float4 o0, o1;
        o0.x = acc[0]*inv + bflo(hn.x) + b0.x;
        o0.y = acc[1]*inv + bfhi(hn.x) + b0.y;
        o0.z = acc[2]*inv + bflo(hn.y) + b0.z;
        o0.w = acc[3]*inv + bfhi(hn.y) + b0.w;
        o1.x = acc[4]*inv + bflo(hn.z) + b1.x;
        o1.y = acc[5]*inv + bfhi(hn.z) + b1.y;
        o1.z = acc[6]*inv + bflo(hn.w) + b1.z;
        o1.w = acc[7]*inv + bfhi(hn.w) + b1.w;
        float4* op = (float4*)(out + (size_t)n * 128 + c16 * 8);
        op[0] = o0; op[1] = o1;
    }
}

extern "C" void kernel_launch(void* const* d_in, const int* in_sizes, int n_in,
                              void* d_out, int out_size, void* d_ws, size_t ws_size,
                              hipStream_t stream) {
    const float* feats  = (const float*)d_in[0];
    const float* W      = (const float*)d_in[1];
    const float* attn_l = (const float*)d_in[2];
    const float* attn_r = (const float*)d_in[3];
    const float* bias   = (const float*)d_in[4];
    const int*   src    = (const int*)d_in[5];
    const int*   dst    = (const int*)d_in[6];

    const int N = in_sizes[0] / 128;
    const int E = in_sizes[5];
    const int B1 = (N + 1023) / 1024;
    const int N8 = (N + 7) / 8;
    const int CH = (E + CHUNK - 1) / CHUNK;

    float* out = (float*)d_out;
    char*  ws  = (char*)d_ws;
    unsigned short* h = (unsigned short*)ws;           ws += (size_t)N * 128 * 2;
    float* el      = (float*)ws;                       ws += (size_t)N * 8 * 4;
    float* er      = (float*)ws;                       ws += (size_t)N * 8 * 4;
    int*   deg     = (int*)ws;                         ws += (size_t)N * 4;
    int*   rowptr  = (int*)ws;                         ws += (size_t)(N + 1) * 4;
    int*   cursor  = (int*)ws;                         ws += (size_t)N * 4;
    int*   partial = (int*)ws;                         ws += 256 * 4;
    int*   partial_ex = (int*)ws;                      ws += 256 * 4;
    int*   csr_src = (int*)ws;                         ws += (size_t)E * 4;

    hipMemsetAsync(deg, 0, (size_t)N * sizeof(int), stream);

    k_gemm <<<(N + 63) / 64,         256, 0, stream>>>(feats, W, h, N);
    k_eler <<<(N * 8 + 255) / 256,   256, 0, stream>>>(h, attn_l, attn_r, el, er, N);
    k_deg  <<<CH * 8,                256, 0, stream>>>(dst, deg, E, N8);
    k_scan1<<<B1,                    256, 0, stream>>>(deg, rowptr, partial, N);
    k_scan2<<<1,                      64, 0, stream>>>(partial, partial_ex, B1);
    k_scan3<<<B1,                    256, 0, stream>>>(rowptr, cursor, partial_ex, N, E);
    k_fill <<<CH * 8,                256, 0, stream>>>(src, dst, cursor, csr_src, E, N8);
    k_agg  <<<(N + 3) / 4,           256, 0, stream>>>(rowptr, csr_src, el, er, h, bias, out, N);
}